// Round 5
// baseline (1270.702 us; speedup 1.0000x reference)
//
#include <hip/hip_runtime.h>

#define NROWS 1000000
#define NT    31250      // 32-row tiles (1e6 / 32 exactly)
#define TPB   4          // tiles per wave-batch
#define NBATCH ((NT + TPB - 1) / TPB)   // 7813
#define MLP_BLOCKS 977   // 3908 waves -> ~2 batches/wave

typedef __bf16 bf16x8 __attribute__((ext_vector_type(8)));
typedef float  f32x16 __attribute__((ext_vector_type(16)));

// ---------------------------------------------------------------------------
// Kernel 1: per-tile (32 rows) nonzero counts.
// ---------------------------------------------------------------------------
__global__ __launch_bounds__(256) void count_kernel(
    const int* __restrict__ mask, int* __restrict__ counts) {
  int tid = threadIdx.x;
  int row = blockIdx.x * 256 + tid;
  int cnt = 0;
  if (row < NROWS) {
    const int4* mp = (const int4*)(mask + (long)row * 8);
    int4 a = mp[0], b = mp[1];
    cnt = (a.x != 0) + (a.y != 0) + (a.z != 0) + (a.w != 0) +
          (b.x != 0) + (b.y != 0) + (b.z != 0) + (b.w != 0);
  }
#pragma unroll
  for (int off = 1; off < 32; off <<= 1) cnt += __shfl_xor(cnt, off, 32);
  int tile = row >> 5;
  if ((tid & 31) == 0 && row < NROWS) counts[tile] = cnt;
}

// ---------------------------------------------------------------------------
// Kernel 2: exclusive scan of 31250 tile counts (single block).
// ---------------------------------------------------------------------------
__global__ __launch_bounds__(1024) void scan_kernel(
    const int* __restrict__ counts, int* __restrict__ offs) {
  __shared__ int lds[1024];
  int tid = threadIdx.x;
  int base = tid * 32;
  int c[32];
  int s = 0;
#pragma unroll
  for (int i = 0; i < 32; ++i) {
    int idx = base + i;
    int v = (idx < NT) ? counts[idx] : 0;
    c[i] = s;
    s += v;
  }
  lds[tid] = s;
  __syncthreads();
  for (int off = 1; off < 1024; off <<= 1) {
    int v = lds[tid];
    int add = (tid >= off) ? lds[tid - off] : 0;
    __syncthreads();
    lds[tid] = v + add;
    __syncthreads();
  }
  int tb = lds[tid] - s;
#pragma unroll
  for (int i = 0; i < 32; ++i) {
    int idx = base + i;
    if (idx < NT) offs[idx] = tb + c[i];
  }
}

// ---------------------------------------------------------------------------
// Kernel 3: fused MFMA MLP + ordered compaction.
// Swapped operands: D[q][n] = (W0^T)[q][k] * X^T[k][n]; bias via C operand.
// Pressure control: opaque lic blocks LICM of LDS loads across batches;
// sched_barrier(0) per dq iteration keeps per-iteration working set small.
// ---------------------------------------------------------------------------
__global__ __launch_bounds__(256) void mlp_kernel(
    const float* __restrict__ x, const int* __restrict__ mask,
    const float* __restrict__ w0, const float* __restrict__ b0,
    const float* __restrict__ w1, const float* __restrict__ b1,
    const int* __restrict__ tile_off, float* __restrict__ out) {
  __shared__ __bf16 sA[32 * 64 * 8];  // 32 frags x 64 lanes x 8 bf16 = 32 KB
  __shared__ float sB0[512];
  __shared__ float sW1[512];

  int tid = threadIdx.x;

  // ---- cooperative fill: W0^T fragments (bf16), b0, w1 ----
  // fi = i*256+tid -> adjacent threads write adjacent 16B: conflict-free.
#pragma unroll
  for (int i = 0; i < 8; ++i) {
    int fi = i * 256 + tid;  // 0..2047 = frag(32) x lane(64)
    int frag = fi >> 6;
    int lane = fi & 63;
    int d = frag >> 2;
    int qg = (frag >> 1) & 1;
    int kc = frag & 1;
    int q = qg * 32 + (lane & 31);           // A row m -> hidden index
    int kbase = kc * 16 + (lane >> 5) * 8;   // k chunk per half-wave
    bf16x8 v;
#pragma unroll
    for (int j = 0; j < 8; ++j)
      v[j] = (__bf16)w0[d * 2048 + (kbase + j) * 64 + q];
    *(bf16x8*)&sA[fi * 8] = v;
  }
  if (tid < 128) {
    *(float4*)&sB0[tid * 4] = *(const float4*)&b0[tid * 4];
  } else {
    int t2 = tid - 128;
    *(float4*)&sW1[t2 * 4] = *(const float4*)&w1[t2 * 4];
  }
  __syncthreads();

  int l = tid & 63;
  int l31 = l & 31;
  int half = l >> 5;
  int wv = (blockIdx.x << 2) + (tid >> 6);
  int W = gridDim.x << 2;

  for (int b = wv; b < NBATCH; b += W) {
    int lic = 0;
    asm volatile("" : "+v"(lic));  // opaque 0: blocks cross-batch LICM/CSE
    int t0 = b * TPB;

    // ---- load x for 4 tiles -> B fragments (row n = l&31, k per half) ----
    bf16x8 Bf[TPB][2];
#pragma unroll
    for (int t = 0; t < TPB; ++t) {
      int tile = t0 + t;
      if (tile >= NT) tile = NT - 1;  // clamp; stores guarded later
      int row = tile * 32 + l31;
      const float* xp = x + row * 32 + half * 8;
#pragma unroll
      for (int kc = 0; kc < 2; ++kc) {
        float4 f0 = *(const float4*)(xp + kc * 16);
        float4 f1 = *(const float4*)(xp + kc * 16 + 4);
        bf16x8 v;
        v[0] = (__bf16)f0.x; v[1] = (__bf16)f0.y;
        v[2] = (__bf16)f0.z; v[3] = (__bf16)f0.w;
        v[4] = (__bf16)f1.x; v[5] = (__bf16)f1.y;
        v[6] = (__bf16)f1.z; v[7] = (__bf16)f1.w;
        Bf[t][kc] = v;
      }
    }

    float acc[8][TPB];
#pragma unroll
    for (int d = 0; d < 8; ++d)
#pragma unroll
      for (int t = 0; t < TPB; ++t) acc[d][t] = 0.f;

    // ---- 16 fused (d,qg) steps; fenced to keep live set small ----
#pragma unroll
    for (int dq = 0; dq < 16; ++dq) {
      int fragbase = dq * 1024 + l * 8 + lic;  // bf16 elements
      bf16x8 A0 = *(const bf16x8*)&sA[fragbase];
      bf16x8 A1 = *(const bf16x8*)&sA[fragbase + 512];
      // bias (C) and w1 in the D register pattern:
      // reg r -> q = (dq&1)*32 + (r&3) + 8*(r>>2) + 4*half
      int qb = dq * 32 + half * 4 + lic;
      f32x16 C, W1r;
#pragma unroll
      for (int i = 0; i < 4; ++i) {
        float4 cv = *(const float4*)&sB0[qb + i * 8];
        float4 wv4 = *(const float4*)&sW1[qb + i * 8];
        C[i * 4 + 0] = cv.x; C[i * 4 + 1] = cv.y;
        C[i * 4 + 2] = cv.z; C[i * 4 + 3] = cv.w;
        W1r[i * 4 + 0] = wv4.x; W1r[i * 4 + 1] = wv4.y;
        W1r[i * 4 + 2] = wv4.z; W1r[i * 4 + 3] = wv4.w;
      }
#pragma unroll
      for (int t = 0; t < TPB; ++t) {
        f32x16 D = __builtin_amdgcn_mfma_f32_32x32x16_bf16(A0, Bf[t][0], C, 0, 0, 0);
        D = __builtin_amdgcn_mfma_f32_32x32x16_bf16(A1, Bf[t][1], D, 0, 0, 0);
        float a = acc[dq >> 1][t];
#pragma unroll
        for (int r = 0; r < 16; ++r)
          a = fmaf(fmaxf(D[r], 0.f), W1r[r], a);
        acc[dq >> 1][t] = a;
      }
      __builtin_amdgcn_sched_barrier(0);  // keep per-dq working set live-short
    }

    // ---- epilogue: mask, in-tile prefix, half-reduce, ordered scatter ----
#pragma unroll
    for (int t = 0; t < TPB; ++t) {
      int tile = t0 + t;
      bool valid = tile < NT;  // wave-uniform
      int ct = valid ? tile : NT - 1;
      int row = ct * 32 + l31;
      const int4* mp = (const int4*)(mask + (long)row * 8);
      int4 m0 = mp[0], m1 = mp[1];
      unsigned mb = (unsigned)((m0.x != 0) | ((m0.y != 0) << 1) |
                               ((m0.z != 0) << 2) | ((m0.w != 0) << 3) |
                               ((m1.x != 0) << 4) | ((m1.y != 0) << 5) |
                               ((m1.z != 0) << 6) | ((m1.w != 0) << 7));
      int cnt = __popc(mb);
      int incl = cnt;
#pragma unroll
      for (int off = 1; off < 32; off <<= 1) {
        int v = __shfl_up(incl, off, 32);
        if (l31 >= off) incl += v;
      }
      int pos = tile_off[ct] + (incl - cnt);
      float red[8];
#pragma unroll
      for (int d = 0; d < 8; ++d) {
        float s = acc[d][t];
        s += __shfl_xor(s, 32);
        red[d] = s + b1[d];
      }
      int base = pos + (half ? __popc(mb & 0xFu) : 0);
      unsigned nib = (mb >> (half * 4)) & 0xFu;
      if (valid) {
#pragma unroll
        for (int dd = 0; dd < 4; ++dd) {
          if ((nib >> dd) & 1u) {
            float v0 = red[dd], v1 = red[4 + dd];
            out[base] = half ? v1 : v0;  // static indices, cndmask select
            base++;
          }
        }
      }
    }
  }
}

extern "C" void kernel_launch(void* const* d_in, const int* in_sizes, int n_in,
                              void* d_out, int out_size, void* d_ws, size_t ws_size,
                              hipStream_t stream) {
  const float* x    = (const float*)d_in[0];
  const int*   mask = (const int*)d_in[1];
  const float* w0   = (const float*)d_in[2];
  const float* b0   = (const float*)d_in[3];
  const float* w1   = (const float*)d_in[4];
  const float* b1   = (const float*)d_in[5];
  float* out = (float*)d_out;

  int* counts = (int*)d_ws;
  int* offs   = counts + NT;

  count_kernel<<<(NROWS + 255) / 256, 256, 0, stream>>>(mask, counts);
  scan_kernel<<<1, 1024, 0, stream>>>(counts, offs);
  mlp_kernel<<<MLP_BLOCKS, 256, 0, stream>>>(x, mask, w0, b0, w1, b1, offs, out);
}

// Round 6
// 147.792 us; speedup vs baseline: 8.5979x; 8.5979x over previous
//
#include <hip/hip_runtime.h>

#define NROWS 1000000
#define NT    62500        // 16-row tiles (1e6 / 16 exactly)
#define TPB   4            // tiles per wave-batch
#define NBATCH (NT / TPB)  // 15625, exact
#define MLP_BLOCKS 1024    // x4 waves = 4096 waves

typedef __bf16 bf16x8 __attribute__((ext_vector_type(8)));
typedef float  f32x4  __attribute__((ext_vector_type(4)));

// ---------------------------------------------------------------------------
// Kernel 1: per-tile (16 rows) nonzero counts.
// ---------------------------------------------------------------------------
__global__ __launch_bounds__(256) void count_kernel(
    const int* __restrict__ mask, int* __restrict__ counts) {
  int tid = threadIdx.x;
  int row = blockIdx.x * 256 + tid;
  int cnt = 0;
  if (row < NROWS) {
    const int4* mp = (const int4*)(mask + (long)row * 8);
    int4 a = mp[0], b = mp[1];
    cnt = (a.x != 0) + (a.y != 0) + (a.z != 0) + (a.w != 0) +
          (b.x != 0) + (b.y != 0) + (b.z != 0) + (b.w != 0);
  }
#pragma unroll
  for (int off = 1; off < 16; off <<= 1) cnt += __shfl_xor(cnt, off, 16);
  if ((tid & 15) == 0 && row < NROWS) counts[row >> 4] = cnt;
}

// ---------------------------------------------------------------------------
// Kernel 2: exclusive scan of 62500 tile counts (single block, 64/thread).
// ---------------------------------------------------------------------------
__global__ __launch_bounds__(1024) void scan_kernel(
    const int* __restrict__ counts, int* __restrict__ offs) {
  __shared__ int lds[1024];
  int tid = threadIdx.x;
  int base = tid * 64;
  int c[64];
  int s = 0;
#pragma unroll
  for (int i = 0; i < 64; ++i) {
    int idx = base + i;
    int v = (idx < NT) ? counts[idx] : 0;
    c[i] = s;
    s += v;
  }
  lds[tid] = s;
  __syncthreads();
  for (int off = 1; off < 1024; off <<= 1) {
    int v = lds[tid];
    int add = (tid >= off) ? lds[tid - off] : 0;
    __syncthreads();
    lds[tid] = v + add;
    __syncthreads();
  }
  int tb = lds[tid] - s;
#pragma unroll
  for (int i = 0; i < 64; ++i) {
    int idx = base + i;
    if (idx < NT) offs[idx] = tb + c[i];
  }
}

// ---------------------------------------------------------------------------
// Kernel 3: fused 16x16x32-MFMA MLP + ordered compaction.
// Swapped operands: D[q][n] = W0^T-frag x X-frag, bias via C.
// D pattern (m89-verified): col n = l&15, row q = (l>>4)*4 + r (contiguous!)
// -> bias/w1 load as one broadcast ds_read_b128 each; no permutation.
// d-loop is unroll-1 with NO d-indexed register arrays: per-d partials are
// reduced and parked in per-wave LDS sOut, then consumed by the epilogue.
// ---------------------------------------------------------------------------
__global__ __launch_bounds__(256) void mlp_kernel(
    const float* __restrict__ x, const int* __restrict__ mask,
    const float* __restrict__ w0, const float* __restrict__ b0,
    const float* __restrict__ w1, const float* __restrict__ b1,
    const int* __restrict__ tile_off, float* __restrict__ out) {
  __shared__ __bf16 sA[32 * 64 * 8];        // 32 frags(d*4+qb) x 64 lanes x 8
  __shared__ float sB0[512];                // b0 verbatim
  __shared__ float sW1[512];                // w1[:, :, 0] verbatim
  __shared__ float sOut[4 * TPB * 16 * 12]; // per-wave, stride 12 (48B, aligned)

  int tid = threadIdx.x;

  // ---- prologue: stage W0^T fragments (bf16), b0, w1 ----
#pragma unroll
  for (int i = 0; i < 8; ++i) {
    int fi = i * 256 + tid;          // 0..2047
    int frag = fi >> 6;              // d*4 + qb
    int lane = fi & 63;
    int d = frag >> 2, qb = frag & 3;
    int q = qb * 16 + (lane & 15);   // A row m -> hidden index
    int kb = (lane >> 4) * 8;        // k chunk per 16-lane group
    bf16x8 v;
#pragma unroll
    for (int j = 0; j < 8; ++j)
      v[j] = (__bf16)w0[d * 2048 + (kb + j) * 64 + q];
    *(bf16x8*)&sA[fi * 8] = v;
  }
  if (tid < 128) {
    *(float4*)&sB0[tid * 4] = *(const float4*)&b0[tid * 4];
  } else {
    int t2 = tid - 128;
    *(float4*)&sW1[t2 * 4] = *(const float4*)&w1[t2 * 4];
  }
  __syncthreads();

  int l = tid & 63;
  int n = l & 15;          // output row within tile / MFMA col
  int g = l >> 4;          // 16-lane group: k-chunk for A/B, q-subblock for D
  int w = tid >> 6;
  int wv = blockIdx.x * 4 + w;
  const int W = MLP_BLOCKS * 4;
  float* myOut = &sOut[w * (TPB * 16 * 12)];

  for (int b = wv; b < NBATCH; b += W) {
    int t0 = b * TPB;

    // ---- x fragments: B[k][n], n = row-in-tile, k = g*8 + j ----
    bf16x8 xf0, xf1, xf2, xf3;
    {
      const float* xp;
      float4 a, c;
#define LOADX(T, DST)                                              \
      xp = x + (long)((t0 + T) * 16 + n) * 32 + g * 8;             \
      a = *(const float4*)xp; c = *(const float4*)(xp + 4);        \
      DST[0] = (__bf16)a.x; DST[1] = (__bf16)a.y;                  \
      DST[2] = (__bf16)a.z; DST[3] = (__bf16)a.w;                  \
      DST[4] = (__bf16)c.x; DST[5] = (__bf16)c.y;                  \
      DST[6] = (__bf16)c.z; DST[7] = (__bf16)c.w;
      LOADX(0, xf0) LOADX(1, xf1) LOADX(2, xf2) LOADX(3, xf3)
#undef LOADX
    }

#pragma unroll 1
    for (int d = 0; d < 8; ++d) {
      float p0 = 0.f, p1 = 0.f, p2 = 0.f, p3 = 0.f;
#pragma unroll
      for (int qb = 0; qb < 4; ++qb) {
        int frag = d * 4 + qb;
        bf16x8 A  = *(const bf16x8*)&sA[frag * 512 + l * 8];
        f32x4 Cb  = *(const f32x4*)&sB0[frag * 16 + g * 4];  // bias, D pattern
        f32x4 W1r = *(const f32x4*)&sW1[frag * 16 + g * 4];
        f32x4 D0 = __builtin_amdgcn_mfma_f32_16x16x32_bf16(A, xf0, Cb, 0, 0, 0);
        f32x4 D1 = __builtin_amdgcn_mfma_f32_16x16x32_bf16(A, xf1, Cb, 0, 0, 0);
        f32x4 D2 = __builtin_amdgcn_mfma_f32_16x16x32_bf16(A, xf2, Cb, 0, 0, 0);
        f32x4 D3 = __builtin_amdgcn_mfma_f32_16x16x32_bf16(A, xf3, Cb, 0, 0, 0);
#pragma unroll
        for (int r = 0; r < 4; ++r) {
          p0 = fmaf(fmaxf(D0[r], 0.f), W1r[r], p0);
          p1 = fmaf(fmaxf(D1[r], 0.f), W1r[r], p1);
          p2 = fmaf(fmaxf(D2[r], 0.f), W1r[r], p2);
          p3 = fmaf(fmaxf(D3[r], 0.f), W1r[r], p3);
        }
      }
      // reduce the 4 q-subblock groups (butterfly over lane bits 4,5)
      p0 += __shfl_xor(p0, 16); p0 += __shfl_xor(p0, 32);
      p1 += __shfl_xor(p1, 16); p1 += __shfl_xor(p1, 32);
      p2 += __shfl_xor(p2, 16); p2 += __shfl_xor(p2, 32);
      p3 += __shfl_xor(p3, 16); p3 += __shfl_xor(p3, 32);
      float bb = b1[d];
      if (g == 0) {
        myOut[(0 * 16 + n) * 12 + d] = p0 + bb;
        myOut[(1 * 16 + n) * 12 + d] = p1 + bb;
        myOut[(2 * 16 + n) * 12 + d] = p2 + bb;
        myOut[(3 * 16 + n) * 12 + d] = p3 + bb;
      }
    }

    // ---- epilogue: lane l owns row t0*16 + l (tile t0+g, row n) ----
    int row = t0 * 16 + l;
    const int4* mp = (const int4*)(mask + (long)row * 8);
    int4 m0 = mp[0], m1 = mp[1];
    unsigned mb = (unsigned)((m0.x != 0) | ((m0.y != 0) << 1) |
                             ((m0.z != 0) << 2) | ((m0.w != 0) << 3) |
                             ((m1.x != 0) << 4) | ((m1.y != 0) << 5) |
                             ((m1.z != 0) << 6) | ((m1.w != 0) << 7));
    int cnt = __popc(mb);
    int incl = cnt;
#pragma unroll
    for (int off = 1; off < 16; off <<= 1) {
      int v = __shfl_up(incl, off, 16);
      if (n >= off) incl += v;
    }
    int pos = tile_off[t0 + g] + (incl - cnt);
    f32x4 v0 = *(const f32x4*)&myOut[(g * 16 + n) * 12];
    f32x4 v1 = *(const f32x4*)&myOut[(g * 16 + n) * 12 + 4];
#pragma unroll
    for (int dd = 0; dd < 4; ++dd) {
      if ((mb >> dd) & 1u) out[pos++] = v0[dd];
    }
#pragma unroll
    for (int dd = 0; dd < 4; ++dd) {
      if ((mb >> (4 + dd)) & 1u) out[pos++] = v1[dd];
    }
  }
}

extern "C" void kernel_launch(void* const* d_in, const int* in_sizes, int n_in,
                              void* d_out, int out_size, void* d_ws, size_t ws_size,
                              hipStream_t stream) {
  const float* x    = (const float*)d_in[0];
  const int*   mask = (const int*)d_in[1];
  const float* w0   = (const float*)d_in[2];
  const float* b0   = (const float*)d_in[3];
  const float* w1   = (const float*)d_in[4];
  const float* b1   = (const float*)d_in[5];
  float* out = (float*)d_out;

  int* counts = (int*)d_ws;
  int* offs   = counts + NT;

  count_kernel<<<(NROWS + 255) / 256, 256, 0, stream>>>(mask, counts);
  scan_kernel<<<1, 1024, 0, stream>>>(counts, offs);
  mlp_kernel<<<MLP_BLOCKS, 256, 0, stream>>>(x, mask, w0, b0, w1, b1, offs, out);
}

// Round 7
// 92.040 us; speedup vs baseline: 13.8060x; 1.6057x over previous
//
#include <hip/hip_runtime.h>

#define NROWS 1000000
#define NB    3907         // ceil(1e6 / 256) mask blocks
#define NT    62500        // 16-row tiles
#define TPB   4            // tiles per wave-batch
#define NBATCH (NT / TPB)  // 15625, exact
#define MLP_BLOCKS 768     // 256 CUs x 3 blocks (48KB LDS each) exact residency

typedef __bf16 bf16x8 __attribute__((ext_vector_type(8)));
typedef float  f32x4  __attribute__((ext_vector_type(4)));

// ---------------------------------------------------------------------------
// Kernel 1: per-256-row-block nonzero counts (3907 sums).
// ---------------------------------------------------------------------------
__global__ __launch_bounds__(256) void count_kernel(
    const int* __restrict__ mask, int* __restrict__ bsum) {
  int tid = threadIdx.x;
  int row = blockIdx.x * 256 + tid;
  int cnt = 0;
  if (row < NROWS) {
    const int4* mp = (const int4*)(mask + (long)row * 8);
    int4 a = mp[0], b = mp[1];
    cnt = (a.x != 0) + (a.y != 0) + (a.z != 0) + (a.w != 0) +
          (b.x != 0) + (b.y != 0) + (b.z != 0) + (b.w != 0);
  }
#pragma unroll
  for (int off = 1; off < 64; off <<= 1) cnt += __shfl_xor(cnt, off);
  __shared__ int ws[4];
  if ((tid & 63) == 0) ws[tid >> 6] = cnt;
  __syncthreads();
  if (tid == 0) bsum[blockIdx.x] = ws[0] + ws[1] + ws[2] + ws[3];
}

// ---------------------------------------------------------------------------
// Kernel 2: exclusive scan of 3907 block sums (single block, coalesced).
// ---------------------------------------------------------------------------
__global__ __launch_bounds__(1024) void scan_kernel(
    const int* __restrict__ bsum, int* __restrict__ boff) {
  __shared__ int lds[1024];
  int t = threadIdx.x;
  int i0 = t * 4;
  int c0 = (i0 + 0 < NB) ? bsum[i0 + 0] : 0;
  int c1 = (i0 + 1 < NB) ? bsum[i0 + 1] : 0;
  int c2 = (i0 + 2 < NB) ? bsum[i0 + 2] : 0;
  int c3 = (i0 + 3 < NB) ? bsum[i0 + 3] : 0;
  int s = c0 + c1 + c2 + c3;
  lds[t] = s;
  __syncthreads();
  for (int off = 1; off < 1024; off <<= 1) {
    int v = lds[t];
    int add = (t >= off) ? lds[t - off] : 0;
    __syncthreads();
    lds[t] = v + add;
    __syncthreads();
  }
  int excl = lds[t] - s;
  if (i0 + 0 < NB) boff[i0 + 0] = excl;
  excl += c0;
  if (i0 + 1 < NB) boff[i0 + 1] = excl;
  excl += c1;
  if (i0 + 2 < NB) boff[i0 + 2] = excl;
  excl += c2;
  if (i0 + 3 < NB) boff[i0 + 3] = excl;
}

// ---------------------------------------------------------------------------
// Kernel 3: per-row info = (scatter_pos << 8) | mask_bits.
// Block-wide exclusive scan: wave prefix (shfl_up) + cross-wave offsets.
// ---------------------------------------------------------------------------
__global__ __launch_bounds__(256) void expand_kernel(
    const int* __restrict__ mask, const int* __restrict__ boff,
    int* __restrict__ rowinfo) {
  int tid = threadIdx.x;
  int row = blockIdx.x * 256 + tid;
  bool valid = row < NROWS;
  unsigned mb = 0;
  int cnt = 0;
  if (valid) {
    const int4* mp = (const int4*)(mask + (long)row * 8);
    int4 a = mp[0], b = mp[1];
    mb = (unsigned)((a.x != 0) | ((a.y != 0) << 1) | ((a.z != 0) << 2) |
                    ((a.w != 0) << 3) | ((b.x != 0) << 4) | ((b.y != 0) << 5) |
                    ((b.z != 0) << 6) | ((b.w != 0) << 7));
    cnt = __popc(mb);
  }
  int incl = cnt;
#pragma unroll
  for (int off = 1; off < 64; off <<= 1) {
    int v = __shfl_up(incl, off);
    if ((tid & 63) >= off) incl += v;
  }
  __shared__ int wsum[4];
  if ((tid & 63) == 63) wsum[tid >> 6] = incl;
  __syncthreads();
  int w = tid >> 6;
  int wo = 0;
  if (w > 0) wo += wsum[0];
  if (w > 1) wo += wsum[1];
  if (w > 2) wo += wsum[2];
  int pos = boff[blockIdx.x] + wo + (incl - cnt);
  if (valid) rowinfo[row] = (pos << 8) | (int)mb;
}

// ---------------------------------------------------------------------------
// Kernel 4: fused 16x16x32-MFMA MLP + ordered scatter via rowinfo.
// Swapped operands: D[q][n] = W0^T-frag x X-frag, bias via C.
// D pattern (m89-verified): col n = l&15, row q = (l>>4)*4 + r (contiguous).
// ---------------------------------------------------------------------------
__global__ __launch_bounds__(256) void mlp_kernel(
    const float* __restrict__ x, const float* __restrict__ w0,
    const float* __restrict__ b0, const float* __restrict__ w1,
    const float* __restrict__ b1, const int* __restrict__ rowinfo,
    float* __restrict__ out) {
  __shared__ __bf16 sA[32 * 64 * 8];        // 32 frags(d*4+qb) x 64 lanes x 8
  __shared__ float sB0[512];                // b0 verbatim
  __shared__ float sW1[512];                // w1[:, :, 0] verbatim
  __shared__ float sOut[4 * TPB * 16 * 12]; // per-wave rows, stride 12 (48B)

  int tid = threadIdx.x;

  // ---- prologue: stage W0^T fragments (bf16), b0, w1 ----
#pragma unroll
  for (int i = 0; i < 8; ++i) {
    int fi = i * 256 + tid;          // 0..2047
    int frag = fi >> 6;              // d*4 + qb
    int lane = fi & 63;
    int d = frag >> 2, qb = frag & 3;
    int q = qb * 16 + (lane & 15);   // A row m -> hidden index
    int kb = (lane >> 4) * 8;        // k chunk per 16-lane group
    bf16x8 v;
#pragma unroll
    for (int j = 0; j < 8; ++j)
      v[j] = (__bf16)w0[d * 2048 + (kb + j) * 64 + q];
    *(bf16x8*)&sA[fi * 8] = v;
  }
  if (tid < 128) {
    *(float4*)&sB0[tid * 4] = *(const float4*)&b0[tid * 4];
  } else {
    int t2 = tid - 128;
    *(float4*)&sW1[t2 * 4] = *(const float4*)&w1[t2 * 4];
  }
  __syncthreads();

  int l = tid & 63;
  int n = l & 15;          // MFMA col / row-in-tile
  int g = l >> 4;          // 16-lane group
  int w = tid >> 6;
  int wv = blockIdx.x * 4 + w;
  const int W = MLP_BLOCKS * 4;
  float* myOut = &sOut[w * (TPB * 16 * 12)];

  for (int b = wv; b < NBATCH; b += W) {
    int t0 = b * TPB;

    // ---- x fragments: B[k][n], k = g*8 + j ----
    bf16x8 xf0, xf1, xf2, xf3;
    {
      const float* xp;
      float4 a, c;
#define LOADX(T, DST)                                              \
      xp = x + (long)((t0 + T) * 16 + n) * 32 + g * 8;             \
      a = *(const float4*)xp; c = *(const float4*)(xp + 4);        \
      DST[0] = (__bf16)a.x; DST[1] = (__bf16)a.y;                  \
      DST[2] = (__bf16)a.z; DST[3] = (__bf16)a.w;                  \
      DST[4] = (__bf16)c.x; DST[5] = (__bf16)c.y;                  \
      DST[6] = (__bf16)c.z; DST[7] = (__bf16)c.w;
      LOADX(0, xf0) LOADX(1, xf1) LOADX(2, xf2) LOADX(3, xf3)
#undef LOADX
    }

#pragma unroll 1
    for (int d = 0; d < 8; ++d) {
      float p0 = 0.f, p1 = 0.f, p2 = 0.f, p3 = 0.f;
#pragma unroll
      for (int qb = 0; qb < 4; ++qb) {
        int frag = d * 4 + qb;
        bf16x8 A  = *(const bf16x8*)&sA[frag * 512 + l * 8];
        f32x4 Cb  = *(const f32x4*)&sB0[frag * 16 + g * 4];  // bias, D pattern
        f32x4 W1r = *(const f32x4*)&sW1[frag * 16 + g * 4];
        f32x4 D0 = __builtin_amdgcn_mfma_f32_16x16x32_bf16(A, xf0, Cb, 0, 0, 0);
        f32x4 D1 = __builtin_amdgcn_mfma_f32_16x16x32_bf16(A, xf1, Cb, 0, 0, 0);
        f32x4 D2 = __builtin_amdgcn_mfma_f32_16x16x32_bf16(A, xf2, Cb, 0, 0, 0);
        f32x4 D3 = __builtin_amdgcn_mfma_f32_16x16x32_bf16(A, xf3, Cb, 0, 0, 0);
#pragma unroll
        for (int r = 0; r < 4; ++r) {
          p0 = fmaf(fmaxf(D0[r], 0.f), W1r[r], p0);
          p1 = fmaf(fmaxf(D1[r], 0.f), W1r[r], p1);
          p2 = fmaf(fmaxf(D2[r], 0.f), W1r[r], p2);
          p3 = fmaf(fmaxf(D3[r], 0.f), W1r[r], p3);
        }
      }
      // reduce the 4 q-subblock groups (butterfly over lane bits 4,5)
      p0 += __shfl_xor(p0, 16); p0 += __shfl_xor(p0, 32);
      p1 += __shfl_xor(p1, 16); p1 += __shfl_xor(p1, 32);
      p2 += __shfl_xor(p2, 16); p2 += __shfl_xor(p2, 32);
      p3 += __shfl_xor(p3, 16); p3 += __shfl_xor(p3, 32);
      float bb = b1[d];
      if (g == 0) {
        myOut[(0 * 16 + n) * 12 + d] = p0 + bb;
        myOut[(1 * 16 + n) * 12 + d] = p1 + bb;
        myOut[(2 * 16 + n) * 12 + d] = p2 + bb;
        myOut[(3 * 16 + n) * 12 + d] = p3 + bb;
      }
    }

    // ---- epilogue: lane l owns row t0*16 + l; pos/mask precomputed ----
    int row = t0 * 16 + l;
    int info = rowinfo[row];
    unsigned mb = (unsigned)info & 255u;
    int pos = (int)(((unsigned)info) >> 8);
    f32x4 v0 = *(const f32x4*)&myOut[l * 12];
    f32x4 v1 = *(const f32x4*)&myOut[l * 12 + 4];
#pragma unroll
    for (int dd = 0; dd < 4; ++dd) {
      if ((mb >> dd) & 1u) out[pos++] = v0[dd];
    }
#pragma unroll
    for (int dd = 0; dd < 4; ++dd) {
      if ((mb >> (4 + dd)) & 1u) out[pos++] = v1[dd];
    }
  }
}

extern "C" void kernel_launch(void* const* d_in, const int* in_sizes, int n_in,
                              void* d_out, int out_size, void* d_ws, size_t ws_size,
                              hipStream_t stream) {
  const float* x    = (const float*)d_in[0];
  const int*   mask = (const int*)d_in[1];
  const float* w0   = (const float*)d_in[2];
  const float* b0   = (const float*)d_in[3];
  const float* w1   = (const float*)d_in[4];
  const float* b1   = (const float*)d_in[5];
  float* out = (float*)d_out;

  int* bsum    = (int*)d_ws;            // NB ints
  int* boff    = bsum + NB;             // NB ints
  int* rowinfo = boff + NB;             // NROWS ints (~4 MB)

  count_kernel<<<NB, 256, 0, stream>>>(mask, bsum);
  scan_kernel<<<1, 1024, 0, stream>>>(bsum, boff);
  expand_kernel<<<NB, 256, 0, stream>>>(mask, boff, rowinfo);
  mlp_kernel<<<MLP_BLOCKS, 256, 0, stream>>>(x, w0, b0, w1, b1, rowinfo, out);
}

// Round 8
// 89.552 us; speedup vs baseline: 14.1895x; 1.0278x over previous
//
#include <hip/hip_runtime.h>

#define NROWS 1000000
#define NB    3907         // ceil(1e6 / 256) mask blocks
#define NT    62500        // 16-row tiles
#define TPB   4            // tiles per wave-batch
#define NBATCH (NT / TPB)  // 15625, exact
#define MLP_BLOCKS 1024    // 256 CUs x 4 blocks (34KB LDS each) exact residency

typedef __bf16 bf16x8 __attribute__((ext_vector_type(8)));
typedef float  f32x4  __attribute__((ext_vector_type(4)));

// ---------------------------------------------------------------------------
// Kernel 1: per-256-row-block nonzero counts (3907 sums).
// ---------------------------------------------------------------------------
__global__ __launch_bounds__(256) void count_kernel(
    const int* __restrict__ mask, int* __restrict__ bsum) {
  int tid = threadIdx.x;
  int row = blockIdx.x * 256 + tid;
  int cnt = 0;
  if (row < NROWS) {
    const int4* mp = (const int4*)(mask + (long)row * 8);
    int4 a = mp[0], b = mp[1];
    cnt = (a.x != 0) + (a.y != 0) + (a.z != 0) + (a.w != 0) +
          (b.x != 0) + (b.y != 0) + (b.z != 0) + (b.w != 0);
  }
#pragma unroll
  for (int off = 1; off < 64; off <<= 1) cnt += __shfl_xor(cnt, off);
  __shared__ int ws[4];
  if ((tid & 63) == 0) ws[tid >> 6] = cnt;
  __syncthreads();
  if (tid == 0) bsum[blockIdx.x] = ws[0] + ws[1] + ws[2] + ws[3];
}

// ---------------------------------------------------------------------------
// Kernel 2: exclusive scan of 3907 block sums (single block, coalesced).
// ---------------------------------------------------------------------------
__global__ __launch_bounds__(1024) void scan_kernel(
    const int* __restrict__ bsum, int* __restrict__ boff) {
  __shared__ int lds[1024];
  int t = threadIdx.x;
  int i0 = t * 4;
  int c0 = (i0 + 0 < NB) ? bsum[i0 + 0] : 0;
  int c1 = (i0 + 1 < NB) ? bsum[i0 + 1] : 0;
  int c2 = (i0 + 2 < NB) ? bsum[i0 + 2] : 0;
  int c3 = (i0 + 3 < NB) ? bsum[i0 + 3] : 0;
  int s = c0 + c1 + c2 + c3;
  lds[t] = s;
  __syncthreads();
  for (int off = 1; off < 1024; off <<= 1) {
    int v = lds[t];
    int add = (t >= off) ? lds[t - off] : 0;
    __syncthreads();
    lds[t] = v + add;
    __syncthreads();
  }
  int excl = lds[t] - s;
  if (i0 + 0 < NB) boff[i0 + 0] = excl;
  excl += c0;
  if (i0 + 1 < NB) boff[i0 + 1] = excl;
  excl += c1;
  if (i0 + 2 < NB) boff[i0 + 2] = excl;
  excl += c2;
  if (i0 + 3 < NB) boff[i0 + 3] = excl;
}

// ---------------------------------------------------------------------------
// Kernel 3: per-row info = (scatter_pos << 8) | mask_bits.
// ---------------------------------------------------------------------------
__global__ __launch_bounds__(256) void expand_kernel(
    const int* __restrict__ mask, const int* __restrict__ boff,
    int* __restrict__ rowinfo) {
  int tid = threadIdx.x;
  int row = blockIdx.x * 256 + tid;
  bool valid = row < NROWS;
  unsigned mb = 0;
  int cnt = 0;
  if (valid) {
    const int4* mp = (const int4*)(mask + (long)row * 8);
    int4 a = mp[0], b = mp[1];
    mb = (unsigned)((a.x != 0) | ((a.y != 0) << 1) | ((a.z != 0) << 2) |
                    ((a.w != 0) << 3) | ((b.x != 0) << 4) | ((b.y != 0) << 5) |
                    ((b.z != 0) << 6) | ((b.w != 0) << 7));
    cnt = __popc(mb);
  }
  int incl = cnt;
#pragma unroll
  for (int off = 1; off < 64; off <<= 1) {
    int v = __shfl_up(incl, off);
    if ((tid & 63) >= off) incl += v;
  }
  __shared__ int wsum[4];
  if ((tid & 63) == 63) wsum[tid >> 6] = incl;
  __syncthreads();
  int w = tid >> 6;
  int wo = 0;
  if (w > 0) wo += wsum[0];
  if (w > 1) wo += wsum[1];
  if (w > 2) wo += wsum[2];
  int pos = boff[blockIdx.x] + wo + (incl - cnt);
  if (valid) rowinfo[row] = (pos << 8) | (int)mb;
}

// ---------------------------------------------------------------------------
// Kernel 4: both MLP layers on MFMA + ordered scatter via rowinfo.
// Layer-0: D0[Λ][n] = W0frag x Xfrag + b0frag, hidden label Λ = frag*16 + m
//   (D layout m89-verified: col n = l&15, row m = (l>>4)*4 + r).
// Layer-1 (zero-shuffle): lane-local D0 regs of frag pair (2c1,2c1+1) ARE the
//   K=32 B-fragment slot-for-slot; A2 = block-diag w1 frag (nonzero only at
//   row m = c1>>1), built by cndmask from 8 persistent VGPRs; C-seed = b1.
//   out rows d=g*4+r live in lanes g<2 -> direct compaction scatter.
// ---------------------------------------------------------------------------
__global__ __launch_bounds__(256, 4) void mlp_kernel(
    const float* __restrict__ x, const float* __restrict__ w0,
    const float* __restrict__ b0, const float* __restrict__ w1,
    const float* __restrict__ b1, const int* __restrict__ rowinfo,
    float* __restrict__ out) {
  __shared__ __bf16 sA[32 * 64 * 8];   // 32 frags x 64 lanes x 8 bf16 = 32 KB
  __shared__ float sB0[512];           // b0 verbatim (frag-sliced reads)

  int tid = threadIdx.x;

  // ---- prologue: stage W0^T fragments (bf16) + b0 ----
#pragma unroll
  for (int i = 0; i < 8; ++i) {
    int fi = i * 256 + tid;          // 0..2047
    int frag = fi >> 6;              // hidden-block 0..31 (label = frag*16+m)
    int lane = fi & 63;
    int d = frag >> 2, qb = frag & 3;
    int q = qb * 16 + (lane & 15);   // within-head hidden index
    int kb = (lane >> 4) * 8;        // k chunk per 16-lane group
    bf16x8 v;
#pragma unroll
    for (int j = 0; j < 8; ++j)
      v[j] = (__bf16)w0[d * 2048 + (kb + j) * 64 + q];
    *(bf16x8*)&sA[fi * 8] = v;
  }
  if (tid < 128) *(float4*)&sB0[tid * 4] = *(const float4*)&b0[tid * 4];
  __syncthreads();

  int l = tid & 63;
  int n = l & 15;          // MFMA col / row-in-tile; also A2 row index m
  int g = l >> 4;          // 16-lane group

  // ---- persistent per-lane w1 fragments (labels c1=2n even / 2n+1 odd) ----
  bf16x8 w1A, w1B;
  bool ownrow = (n < 8);
#pragma unroll
  for (int j = 0; j < 8; ++j) {
    int off = (j >> 2) * 16 + g * 4 + (j & 3);
    w1A[j] = ownrow ? (__bf16)w1[n * 64 + off]      : (__bf16)0.f;
    w1B[j] = ownrow ? (__bf16)w1[n * 64 + 32 + off] : (__bf16)0.f;
  }
  int4 w1Ai = *(int4*)&w1A;
  int4 w1Bi = *(int4*)&w1B;
  f32x4 b1C;
#pragma unroll
  for (int r = 0; r < 4; ++r) b1C[r] = b1[(g * 4 + r) & 7];

  int w = tid >> 6;
  int wv = blockIdx.x * 4 + w;
  const int W = MLP_BLOCKS * 4;

  for (int b = wv; b < NBATCH; b += W) {
    int t0 = b * TPB;

    // ---- x fragments: B[k][n], k-slot (g,j) -> feature g*8+j ----
    bf16x8 xf0, xf1, xf2, xf3;
    {
      const float* xp;
      float4 a, c;
#define LOADX(T, DST)                                              \
      xp = x + (long)((t0 + T) * 16 + n) * 32 + g * 8;             \
      a = *(const float4*)xp; c = *(const float4*)(xp + 4);        \
      DST[0] = (__bf16)a.x; DST[1] = (__bf16)a.y;                  \
      DST[2] = (__bf16)a.z; DST[3] = (__bf16)a.w;                  \
      DST[4] = (__bf16)c.x; DST[5] = (__bf16)c.y;                  \
      DST[6] = (__bf16)c.z; DST[7] = (__bf16)c.w;
      LOADX(0, xf0) LOADX(1, xf1) LOADX(2, xf2) LOADX(3, xf3)
#undef LOADX
    }

    f32x4 O0 = b1C, O1 = b1C, O2 = b1C, O3 = b1C;

#pragma unroll 1
    for (int cp = 0; cp < 8; ++cp) {   // head cp; c1 = 2cp (w1A), 2cp+1 (w1B)
      bool own = (n == cp);
      int4 z4 = {0, 0, 0, 0};
      int4 A2ai = own ? w1Ai : z4;     // 4 cndmask each
      int4 A2bi = own ? w1Bi : z4;
      bf16x8 A2a = *(bf16x8*)&A2ai;
      bf16x8 A2b = *(bf16x8*)&A2bi;
      int fb = cp * 4;                 // 4 layer-0 frags this head
      bf16x8 Aw0 = *(const bf16x8*)&sA[(fb + 0) * 512 + l * 8];
      bf16x8 Aw1 = *(const bf16x8*)&sA[(fb + 1) * 512 + l * 8];
      bf16x8 Aw2 = *(const bf16x8*)&sA[(fb + 2) * 512 + l * 8];
      bf16x8 Aw3 = *(const bf16x8*)&sA[(fb + 3) * 512 + l * 8];
      f32x4 C0 = *(const f32x4*)&sB0[(fb + 0) * 16 + g * 4];
      f32x4 C1 = *(const f32x4*)&sB0[(fb + 1) * 16 + g * 4];
      f32x4 C2 = *(const f32x4*)&sB0[(fb + 2) * 16 + g * 4];
      f32x4 C3 = *(const f32x4*)&sB0[(fb + 3) * 16 + g * 4];

#define TILE(XF, OD) {                                                        \
      f32x4 Da = __builtin_amdgcn_mfma_f32_16x16x32_bf16(Aw0, XF, C0, 0,0,0); \
      f32x4 Db = __builtin_amdgcn_mfma_f32_16x16x32_bf16(Aw1, XF, C1, 0,0,0); \
      bf16x8 B2;                                                              \
      B2[0] = (__bf16)fmaxf(Da[0], 0.f); B2[1] = (__bf16)fmaxf(Da[1], 0.f);   \
      B2[2] = (__bf16)fmaxf(Da[2], 0.f); B2[3] = (__bf16)fmaxf(Da[3], 0.f);   \
      B2[4] = (__bf16)fmaxf(Db[0], 0.f); B2[5] = (__bf16)fmaxf(Db[1], 0.f);   \
      B2[6] = (__bf16)fmaxf(Db[2], 0.f); B2[7] = (__bf16)fmaxf(Db[3], 0.f);   \
      OD = __builtin_amdgcn_mfma_f32_16x16x32_bf16(A2a, B2, OD, 0, 0, 0);     \
      f32x4 Dc = __builtin_amdgcn_mfma_f32_16x16x32_bf16(Aw2, XF, C2, 0,0,0); \
      f32x4 Dd = __builtin_amdgcn_mfma_f32_16x16x32_bf16(Aw3, XF, C3, 0,0,0); \
      bf16x8 B3;                                                              \
      B3[0] = (__bf16)fmaxf(Dc[0], 0.f); B3[1] = (__bf16)fmaxf(Dc[1], 0.f);   \
      B3[2] = (__bf16)fmaxf(Dc[2], 0.f); B3[3] = (__bf16)fmaxf(Dc[3], 0.f);   \
      B3[4] = (__bf16)fmaxf(Dd[0], 0.f); B3[5] = (__bf16)fmaxf(Dd[1], 0.f);   \
      B3[6] = (__bf16)fmaxf(Dd[2], 0.f); B3[7] = (__bf16)fmaxf(Dd[3], 0.f);   \
      OD = __builtin_amdgcn_mfma_f32_16x16x32_bf16(A2b, B3, OD, 0, 0, 0); }
      TILE(xf0, O0) TILE(xf1, O1) TILE(xf2, O2) TILE(xf3, O3)
#undef TILE
    }

    // ---- epilogue: lanes g<2 hold out[d=g*4+r][n]; ordered scatter ----
    if (g < 2) {
#define EPI(T, OD) {                                                     \
      int row = (t0 + T) * 16 + n;                                       \
      int info = rowinfo[row];                                           \
      unsigned mb = (unsigned)info & 255u;                               \
      int pos = (int)(((unsigned)info) >> 8) +                           \
                (g ? __popc(mb & 0xFu) : 0);                             \
      unsigned nib = (mb >> (g * 4)) & 0xFu;                             \
      if (nib & 1u) { out[pos] = OD[0]; pos++; }                         \
      if (nib & 2u) { out[pos] = OD[1]; pos++; }                         \
      if (nib & 4u) { out[pos] = OD[2]; pos++; }                         \
      if (nib & 8u) { out[pos] = OD[3]; }                                }
      EPI(0, O0) EPI(1, O1) EPI(2, O2) EPI(3, O3)
#undef EPI
    }
  }
}

extern "C" void kernel_launch(void* const* d_in, const int* in_sizes, int n_in,
                              void* d_out, int out_size, void* d_ws, size_t ws_size,
                              hipStream_t stream) {
  const float* x    = (const float*)d_in[0];
  const int*   mask = (const int*)d_in[1];
  const float* w0   = (const float*)d_in[2];
  const float* b0   = (const float*)d_in[3];
  const float* w1   = (const float*)d_in[4];
  const float* b1   = (const float*)d_in[5];
  float* out = (float*)d_out;

  int* bsum    = (int*)d_ws;            // NB ints
  int* boff    = bsum + NB;             // NB ints
  int* rowinfo = boff + NB;             // NROWS ints (~4 MB)

  count_kernel<<<NB, 256, 0, stream>>>(mask, bsum);
  scan_kernel<<<1, 1024, 0, stream>>>(bsum, boff);
  expand_kernel<<<NB, 256, 0, stream>>>(mask, boff, rowinfo);
  mlp_kernel<<<MLP_BLOCKS, 256, 0, stream>>>(x, w0, b0, w1, b1, rowinfo, out);
}